// Round 2
// baseline (3033.844 us; speedup 1.0000x reference)
//
#include <hip/hip_runtime.h>
#include <hip/hip_bf16.h>
#include <cstdio>

#define DEV __device__ __forceinline__

constexpr int BB  = 128;   // batch
constexpr int TT  = 512;   // seq len
constexpr int HH  = 128;   // concat hidden
constexpr int H2  = 64;    // per-direction hidden
constexpr int G4  = 256;   // 4*H2 (bilstm gates)
constexpr int GM  = 512;   // 4*HH (mve gates)
constexpr int BCL = 8;     // batch rows per bilstm block
constexpr int NBL = BB / BCL;   // 16
constexpr int BCM = 2;     // batch rows per mve block
constexpr int NBM = BB / BCM;   // 64

DEV float fsigm(float x) { return 1.f / (1.f + __expf(-x)); }
DEV float ftanh(float x) { return 1.f - 2.f / (__expf(2.f * x) + 1.f); }

DEV unsigned short f2bf(float x) {
    __hip_bfloat16 h = __float2bfloat16(x);
    unsigned short u;
    __builtin_memcpy(&u, &h, 2);
    return u;
}
DEV float xload(const float* p) { return *p; }
DEV float xload(const unsigned short* p) {
    __hip_bfloat16 h;
    __builtin_memcpy(&h, p, 2);
    return __bfloat162float(h);
}

// ---------------------------------------------------------------- bi-LSTM ---
struct BiArgs {
    const float* x[7];
    const float* Wih[2];
    const float* Whh[2];
    const float* bih[2];
    const float* bhh[2];
    float* outs;   // [3][B][T][HH]  (traj p-4), fwd cols 0..63, bwd cols 64..127
    float* hid;    // [7][B][HH]
};

__global__ __launch_bounds__(256) void k_bilstm(BiArgs a) {
    const int blk  = blockIdx.x;
    const int prob = blk / NBL;            // 0..13
    const int p    = prob >> 1;            // input 0..6
    const int dir  = prob & 1;             // 0 fwd, 1 bwd
    const int b0   = (blk % NBL) * BCL;
    const int j    = threadIdx.x;          // gate row 0..255

    float w[H2];
    {
        const float4* w4 = (const float4*)(a.Whh[dir] + (size_t)j * H2);
#pragma unroll
        for (int k4 = 0; k4 < H2 / 4; ++k4) {
            float4 v = w4[k4];
            w[4*k4+0] = v.x; w[4*k4+1] = v.y; w[4*k4+2] = v.z; w[4*k4+3] = v.w;
        }
    }
    const float wx0  = a.Wih[dir][j * 2 + 0];
    const float wx1  = a.Wih[dir][j * 2 + 1];
    const float bias = a.bih[dir][j] + a.bhh[dir][j];

    __shared__ float hL[BCL][H2];
    __shared__ float xL[BCL][2];
    __shared__ float gL[BCL][G4];

    for (int i = j; i < BCL * H2; i += 256) ((float*)hL)[i] = 0.f;
    float c0 = 0.f, c1 = 0.f;

    const float* xg = a.x[p];
    float xr = 0.f;
    if (j < BCL * 2) {
        int bb = j >> 1, comp = j & 1;
        int trow = dir ? (TT - 1) : 0;
        xr = xg[((size_t)(b0 + bb) * TT + trow) * 2 + comp];
    }
    const bool isTraj = (p >= 4);
    float* outp = a.outs + (size_t)(isTraj ? (p - 4) : 0) * BB * TT * HH;
    __syncthreads();

    for (int t = 0; t < TT; ++t) {
        if (j < BCL * 2) xL[j >> 1][j & 1] = xr;
        __syncthreads();
        // prefetch next step's x
        if (j < BCL * 2 && t + 1 < TT) {
            int bb = j >> 1, comp = j & 1;
            int trow = dir ? (TT - 2 - t) : (t + 1);
            xr = xg[((size_t)(b0 + bb) * TT + trow) * 2 + comp];
        }
        // gates: g[b][j] = bias + x.Wih + h.Whh
#pragma unroll
        for (int b = 0; b < BCL; ++b) {
            float acc = bias + wx0 * xL[b][0] + wx1 * xL[b][1];
            const float4* h4 = (const float4*)hL[b];
#pragma unroll
            for (int k4 = 0; k4 < H2 / 4; ++k4) {
                float4 hv = h4[k4];
                acc += hv.x * w[4*k4+0] + hv.y * w[4*k4+1] +
                       hv.z * w[4*k4+2] + hv.w * w[4*k4+3];
            }
            gL[b][j] = acc;
        }
        __syncthreads();
        // update: BCL*H2 = 512 pairs, 2 per thread
#pragma unroll
        for (int r = 0; r < 2; ++r) {
            int pr = j + 256 * r;
            int b = pr >> 6, idx = pr & 63;
            float gi = gL[b][idx], gf = gL[b][H2 + idx];
            float gg = gL[b][2 * H2 + idx], go = gL[b][3 * H2 + idx];
            float& c = r ? c1 : c0;
            c = fsigm(gf) * c + fsigm(gi) * ftanh(gg);
            float h = fsigm(go) * ftanh(c);
            hL[b][idx] = h;
            if (isTraj) {
                int tcol = dir ? (TT - 1 - t) : t;
                outp[((size_t)(b0 + b) * TT + tcol) * HH + dir * H2 + idx] = h;
            }
            if (t == TT - 1)
                a.hid[((size_t)p * BB + b0 + b) * HH + dir * H2 + idx] = h;
        }
        __syncthreads();
    }
}

// -------------------------------------------- mve Wih_x transpose (one-off) --
__global__ void k_wxT(const float* __restrict__ Wm, float* __restrict__ WxT) {
    int idx = blockIdx.x * 256 + threadIdx.x;   // 65536
    int k = idx >> 9, j = idx & 511;
    WxT[(size_t)k * GM + j] = Wm[(size_t)j * (2 * HH) + k];
}

// --------------------------------- xproj GEMM: [M=B*T,128] x [128,512] -------
template <typename XT>
__global__ __launch_bounds__(256) void k_xproj(const float* __restrict__ A,
                                               const float* __restrict__ WxT,
                                               XT* __restrict__ C) {
    __shared__ float As[64][128];
    __shared__ float Ws[128][64];
    const int m0 = blockIdx.x * 64;
    const int n0 = blockIdx.y * 64;
    const int tid = threadIdx.x;
#pragma unroll
    for (int it = 0; it < 8; ++it) {
        int lin = it * 256 + tid;          // 0..2047
        int m = lin >> 5, k4 = lin & 31;
        float4 v = ((const float4*)(A + (size_t)(m0 + m) * HH))[k4];
        *(float4*)&As[m][4 * k4] = v;
    }
#pragma unroll
    for (int it = 0; it < 8; ++it) {
        int lin = it * 256 + tid;          // 0..2047
        int k = lin >> 4, n4 = lin & 15;   // full 64-col tile (FIXED)
        float4 v = ((const float4*)(WxT + (size_t)k * GM + n0))[n4];
        *(float4*)&Ws[k][4 * n4] = v;
    }
    __syncthreads();
    const int tm = (tid >> 4) << 2;
    const int tn = (tid & 15) << 2;
    float acc[4][4];
#pragma unroll
    for (int i = 0; i < 4; ++i)
        acc[i][0] = acc[i][1] = acc[i][2] = acc[i][3] = 0.f;
#pragma unroll
    for (int k4 = 0; k4 < 32; ++k4) {
        float4 av0 = *(const float4*)&As[tm + 0][4 * k4];
        float4 av1 = *(const float4*)&As[tm + 1][4 * k4];
        float4 av2 = *(const float4*)&As[tm + 2][4 * k4];
        float4 av3 = *(const float4*)&As[tm + 3][4 * k4];
        float4 wv0 = *(const float4*)&Ws[4 * k4 + 0][tn];
        float4 wv1 = *(const float4*)&Ws[4 * k4 + 1][tn];
        float4 wv2 = *(const float4*)&Ws[4 * k4 + 2][tn];
        float4 wv3 = *(const float4*)&Ws[4 * k4 + 3][tn];
#define ROWX(i, AV)                                                        \
        acc[i][0] += AV.x*wv0.x + AV.y*wv1.x + AV.z*wv2.x + AV.w*wv3.x;     \
        acc[i][1] += AV.x*wv0.y + AV.y*wv1.y + AV.z*wv2.y + AV.w*wv3.y;     \
        acc[i][2] += AV.x*wv0.z + AV.y*wv1.z + AV.z*wv2.z + AV.w*wv3.z;     \
        acc[i][3] += AV.x*wv0.w + AV.y*wv1.w + AV.z*wv2.w + AV.w*wv3.w;
        ROWX(0, av0) ROWX(1, av1) ROWX(2, av2) ROWX(3, av3)
#undef ROWX
    }
#pragma unroll
    for (int i = 0; i < 4; ++i) {
        size_t row = (size_t)(m0 + tm + i);
        XT* cp = C + row * GM + n0 + tn;
        if constexpr (sizeof(XT) == 4) {
            *(float4*)cp = make_float4(acc[i][0], acc[i][1], acc[i][2], acc[i][3]);
        } else {
            ushort4 u;
            u.x = f2bf(acc[i][0]); u.y = f2bf(acc[i][1]);
            u.z = f2bf(acc[i][2]); u.w = f2bf(acc[i][3]);
            *(ushort4*)cp = u;
        }
    }
}

// ------------------------------------------------------------- mve scan -----
struct MveArgs {
    const void* xp;         // xproj (XT), per-traj stride xp_stride (elements)
    size_t xp_stride;
    const float* hidl;      // hid + 4*B*HH  ([3][B][HH])
    const float* Whh;       // [512][128]
    const float* Wih;       // [512][256] (uses cols 128..255)
    const float* bih;
    const float* bhh;
    float* mout;            // d_out + 512 ([3][B][T][HH]) cell states
    int traj0;
};

template <typename XT>
__global__ __launch_bounds__(512) void k_mve(MveArgs a) {
    const int blk = blockIdx.x;
    const int tr = blk / NBM;
    const int traj = a.traj0 + tr;
    const int b0 = (blk % NBM) * BCM;
    const int j = threadIdx.x;   // gate row 0..511

    float w[HH];
    {
        const float4* w4 = (const float4*)(a.Whh + (size_t)j * HH);
#pragma unroll
        for (int k4 = 0; k4 < HH / 4; ++k4) {
            float4 v = w4[k4];
            w[4*k4+0] = v.x; w[4*k4+1] = v.y; w[4*k4+2] = v.z; w[4*k4+3] = v.w;
        }
    }
    __shared__ float hL[BCM][HH];
    __shared__ float gL[BCM][GM];
    if (j < BCM * HH) {
        int b = j >> 7, k = j & 127;
        hL[b][k] = a.hidl[((size_t)traj * BB + b0 + b) * HH + k];
    }
    __syncthreads();
    const float bias = a.bih[j] + a.bhh[j];
    float hp0 = bias, hp1 = bias;
    {
        const float4* wl4 = (const float4*)(a.Wih + (size_t)j * (2 * HH) + HH);
#pragma unroll
        for (int k4 = 0; k4 < HH / 4; ++k4) {
            float4 wv = wl4[k4];
            float4 h0 = ((const float4*)hL[0])[k4];
            float4 h1 = ((const float4*)hL[1])[k4];
            hp0 += wv.x*h0.x + wv.y*h0.y + wv.z*h0.z + wv.w*h0.w;
            hp1 += wv.x*h1.x + wv.y*h1.y + wv.z*h1.z + wv.w*h1.w;
        }
    }
    __syncthreads();
    if (j < BCM * HH) ((float*)hL)[j] = 0.f;

    const XT* xpp = (const XT*)a.xp + (size_t)tr * a.xp_stride;
    float* mo = a.mout + (size_t)traj * BB * TT * HH;
    float xr0 = xload(&xpp[((size_t)(b0 + 0) * TT + 0) * GM + j]);
    float xr1 = xload(&xpp[((size_t)(b0 + 1) * TT + 0) * GM + j]);
    float cc = 0.f;
    __syncthreads();

    for (int t = 0; t < TT; ++t) {
        float acc0 = hp0 + xr0, acc1 = hp1 + xr1;
#pragma unroll
        for (int k4 = 0; k4 < HH / 4; ++k4) {
            float4 h0 = ((const float4*)hL[0])[k4];
            float4 h1 = ((const float4*)hL[1])[k4];
            acc0 += h0.x*w[4*k4+0] + h0.y*w[4*k4+1] + h0.z*w[4*k4+2] + h0.w*w[4*k4+3];
            acc1 += h1.x*w[4*k4+0] + h1.y*w[4*k4+1] + h1.z*w[4*k4+2] + h1.w*w[4*k4+3];
        }
        gL[0][j] = acc0;
        gL[1][j] = acc1;
        __syncthreads();
        if (t + 1 < TT) {
            xr0 = xload(&xpp[((size_t)(b0 + 0) * TT + (t + 1)) * GM + j]);
            xr1 = xload(&xpp[((size_t)(b0 + 1) * TT + (t + 1)) * GM + j]);
        }
        if (j < BCM * HH) {
            int b = j >> 7, idx = j & 127;
            float gi = gL[b][idx], gf = gL[b][HH + idx];
            float gg = gL[b][2 * HH + idx], go = gL[b][3 * HH + idx];
            cc = fsigm(gf) * cc + fsigm(gi) * ftanh(gg);
            float h = fsigm(go) * ftanh(cc);
            hL[b][idx] = h;
            mo[((size_t)(b0 + b) * TT + t) * HH + idx] = cc;  // collects CELL state
        }
        __syncthreads();
    }
}

// ----------------------------------------------------------------- sim ------
__global__ __launch_bounds__(128) void k_sim(const float* __restrict__ hid,
                                             const float* __restrict__ Wi, const float* __restrict__ bi,
                                             const float* __restrict__ Wc, const float* __restrict__ bc,
                                             const float* __restrict__ Wo, const float* __restrict__ bo,
                                             float* __restrict__ simv) {
    int which = blockIdx.x >> 7;
    int b = blockIdx.x & 127;
    int j = threadIdx.x;
    __shared__ float hs[HH];
    hs[j] = hid[((size_t)which * BB + b) * HH + j];
    __syncthreads();
    float ai = bi[j], ac = bc[j], ao = bo[j];
    const float4* wi4 = (const float4*)(Wi + (size_t)j * HH);
    const float4* wc4 = (const float4*)(Wc + (size_t)j * HH);
    const float4* wo4 = (const float4*)(Wo + (size_t)j * HH);
#pragma unroll
    for (int k4 = 0; k4 < HH / 4; ++k4) {
        float4 h = ((const float4*)hs)[k4];
        float4 vi = wi4[k4]; ai += vi.x*h.x + vi.y*h.y + vi.z*h.z + vi.w*h.w;
        float4 vc = wc4[k4]; ac += vc.x*h.x + vc.y*h.y + vc.z*h.z + vc.w*h.w;
        float4 vo = wo4[k4]; ao += vo.x*h.x + vo.y*h.y + vo.z*h.z + vo.w*h.w;
    }
    float Cv = fsigm(ai) * ftanh(ac);
    float v = fsigm(ao) * ftanh(Cv) + hs[j];
    simv[((size_t)which * BB + b) * HH + j] = v;
}

// ------------------------------------------------------------------ l2 ------
__global__ __launch_bounds__(64) void k_l2(const float* __restrict__ simv,
                                           float* __restrict__ out) {
    int p = blockIdx.x >> 7;
    int b = blockIdx.x & 127;
    int aw, cw;
    switch (p) {
        case 0: aw = 0; cw = 2; break;
        case 1: aw = 1; cw = 3; break;
        case 2: aw = 4; cw = 5; break;
        default: aw = 4; cw = 6; break;
    }
    int l = threadIdx.x;
    const float* va = simv + ((size_t)aw * BB + b) * HH;
    const float* vc = simv + ((size_t)cw * BB + b) * HH;
    float d0 = va[l] - vc[l];
    float d1 = va[l + 64] - vc[l + 64];
    float s = d0 * d0 + d1 * d1;
#pragma unroll
    for (int m = 32; m >= 1; m >>= 1) s += __shfl_xor(s, m, 64);
    if (l == 0) out[p * BB + b] = expf(-sqrtf(s));
}

// -------------------------------------------------------------- launcher ----
extern "C" void kernel_launch(void* const* d_in, const int* in_sizes, int n_in,
                              void* d_out_v, int out_size, void* d_ws, size_t ws_size,
                              hipStream_t stream) {
    const float* Wih_f = (const float*)d_in[7];
    const float* Whh_f = (const float*)d_in[8];
    const float* bih_f = (const float*)d_in[9];
    const float* bhh_f = (const float*)d_in[10];
    const float* Wih_b = (const float*)d_in[11];
    const float* Whh_b = (const float*)d_in[12];
    const float* bih_b = (const float*)d_in[13];
    const float* bhh_b = (const float*)d_in[14];
    const float* mWih  = (const float*)d_in[15];
    const float* mWhh  = (const float*)d_in[16];
    const float* mbih  = (const float*)d_in[17];
    const float* mbhh  = (const float*)d_in[18];
    const float* sWi   = (const float*)d_in[19];
    const float* sbi   = (const float*)d_in[20];
    const float* sWc   = (const float*)d_in[21];
    const float* sbc   = (const float*)d_in[22];
    const float* sWo   = (const float*)d_in[23];
    const float* sbo   = (const float*)d_in[24];

    constexpr size_t OUTS_LEN = (size_t)3 * BB * TT * HH;   // 25165824
    constexpr size_t HID_LEN  = (size_t)7 * BB * HH;        // 114688
    constexpr size_t WXT_LEN  = (size_t)HH * GM;            // 65536
    constexpr size_t SIMV_LEN = HID_LEN;
    constexpr size_t XP_LEN   = (size_t)BB * TT * GM;       // 33554432 per traj

    float* ws    = (float*)d_ws;
    float* outs  = ws;
    float* hid   = outs + OUTS_LEN;
    float* wxT   = hid + HID_LEN;
    float* simv  = wxT + WXT_LEN;
    float* xproj = simv + SIMV_LEN;

    size_t fixedB  = (OUTS_LEN + HID_LEN + WXT_LEN + SIMV_LEN) * 4;
    size_t need_pf = fixedB + 3 * XP_LEN * 4;
    size_t need_pb = fixedB + 3 * XP_LEN * 2;
    size_t need_sf = fixedB + XP_LEN * 4;
    int mode = (ws_size >= need_pf) ? 0 : (ws_size >= need_pb) ? 1
             : (ws_size >= need_sf) ? 2 : 3;
    printf("[traj2sim] ws_size=%zu need(pf=%zu pb=%zu sf=%zu) mode=%d out_size=%d\n",
           ws_size, need_pf, need_pb, need_sf, mode, out_size);

    float* dout = (float*)d_out_v;
    float* mout = dout + 512;

    BiArgs ba;
    for (int i = 0; i < 7; ++i) ba.x[i] = (const float*)d_in[i];
    ba.Wih[0] = Wih_f; ba.Wih[1] = Wih_b;
    ba.Whh[0] = Whh_f; ba.Whh[1] = Whh_b;
    ba.bih[0] = bih_f; ba.bih[1] = bih_b;
    ba.bhh[0] = bhh_f; ba.bhh[1] = bhh_b;
    ba.outs = outs; ba.hid = hid;

    k_wxT<<<256, 256, 0, stream>>>(mWih, wxT);
    k_bilstm<<<14 * NBL, 256, 0, stream>>>(ba);

    MveArgs ma;
    ma.hidl = hid + (size_t)4 * BB * HH;
    ma.Whh = mWhh; ma.Wih = mWih; ma.bih = mbih; ma.bhh = mbhh;
    ma.mout = mout;

    dim3 gx(BB * TT / 64, GM / 64);
    if (mode == 0) {
        for (int tr = 0; tr < 3; ++tr)
            k_xproj<float><<<gx, 256, 0, stream>>>(
                outs + (size_t)tr * BB * TT * HH, wxT, xproj + (size_t)tr * XP_LEN);
        ma.xp = xproj; ma.xp_stride = XP_LEN; ma.traj0 = 0;
        k_mve<float><<<3 * NBM, 512, 0, stream>>>(ma);
    } else if (mode == 1) {
        unsigned short* xpb = (unsigned short*)xproj;
        for (int tr = 0; tr < 3; ++tr)
            k_xproj<unsigned short><<<gx, 256, 0, stream>>>(
                outs + (size_t)tr * BB * TT * HH, wxT, xpb + (size_t)tr * XP_LEN);
        ma.xp = xpb; ma.xp_stride = XP_LEN; ma.traj0 = 0;
        k_mve<unsigned short><<<3 * NBM, 512, 0, stream>>>(ma);
    } else if (mode == 2) {
        for (int tr = 0; tr < 3; ++tr) {
            k_xproj<float><<<gx, 256, 0, stream>>>(
                outs + (size_t)tr * BB * TT * HH, wxT, xproj);
            ma.xp = xproj; ma.xp_stride = 0; ma.traj0 = tr;
            k_mve<float><<<NBM, 512, 0, stream>>>(ma);
        }
    } else {
        unsigned short* xpb = (unsigned short*)xproj;
        for (int tr = 0; tr < 3; ++tr) {
            k_xproj<unsigned short><<<gx, 256, 0, stream>>>(
                outs + (size_t)tr * BB * TT * HH, wxT, xpb);
            ma.xp = xpb; ma.xp_stride = 0; ma.traj0 = tr;
            k_mve<unsigned short><<<NBM, 512, 0, stream>>>(ma);
        }
    }

    k_sim<<<7 * BB, 128, 0, stream>>>(hid, sWi, sbi, sWc, sbc, sWo, sbo, simv);
    k_l2<<<4 * BB, 64, 0, stream>>>(simv, dout);
}

// Round 3
// 2216.017 us; speedup vs baseline: 1.3691x; 1.3691x over previous
//
#include <hip/hip_runtime.h>
#include <hip/hip_bf16.h>
#include <cstdio>

#define DEV __device__ __forceinline__

constexpr int BB  = 128;   // batch
constexpr int TT  = 512;   // seq len
constexpr int HH  = 128;   // concat hidden
constexpr int H2  = 64;    // per-direction hidden
constexpr int GM  = 512;   // 4*HH (mve gates)

typedef __attribute__((ext_vector_type(8))) short bf16x8;
typedef __attribute__((ext_vector_type(4))) float f32x4;

#define MFMA16(a_, b_, c_) __builtin_amdgcn_mfma_f32_16x16x32_bf16((a_), (b_), (c_), 0, 0, 0)

DEV float fsigm(float x) { return 1.f / (1.f + __expf(-x)); }
DEV float ftanh(float x) { return 1.f - 2.f / (__expf(2.f * x) + 1.f); }

DEV unsigned short f2bf(float x) {
    __hip_bfloat16 h = __float2bfloat16(x);
    unsigned short u;
    __builtin_memcpy(&u, &h, 2);
    return u;
}
DEV float bfu(unsigned short u) {
    unsigned int x = ((unsigned int)u) << 16;
    float f;
    __builtin_memcpy(&f, &x, 4);
    return f;
}
DEV bf16x8 pack8(const float* f) {
    bf16x8 v;
#pragma unroll
    for (int e = 0; e < 8; ++e) v[e] = (short)f2bf(f[e]);
    return v;
}

// ============================ bi-LSTM (MFMA) ================================
// Gate rows permuted p = 4h+q (q: 0=i,1=f,2=g,3=o). Per (scan, batch16) block:
// G[256p][16b] = Whh_perm[256][64] x Ht[64][16]; lane's 4 acc regs = i,f,g,o
// of cell (h = 16w+4mt+lg, c = lc). One barrier/step.
struct BiArgs {
    const float* x[7];
    const float* Wih[2];
    const float* Whh[2];
    const float* bih[2];
    const float* bhh[2];
    float* outs;   // [3][B][T][HH] fp32 (traj only)
    float* hid;    // [7][B][HH] fp32
};

__global__ __launch_bounds__(256) void k_bilstm_mfma(BiArgs a) {
    const int blk  = blockIdx.x;        // 112
    const int scan = blk >> 3;          // 0..13
    const int prob = scan >> 1;         // 0..6
    const int dir  = scan & 1;
    const int b0   = (blk & 7) * 16;
    const int tid  = threadIdx.x;
    const int w    = tid >> 6;          // wave 0..3
    const int l    = tid & 63;
    const int lg   = l >> 4;            // 0..3
    const int lc   = l & 15;            // batch col / A row

    const float* Whh = a.Whh[dir];
    const float* Wih = a.Wih[dir];

    // A-frags (weights, loop-invariant): rows p = 64w+16mt+lc, k = 32kh+8lg+e
    bf16x8 wf[4][2];
#pragma unroll
    for (int mt = 0; mt < 4; ++mt) {
#pragma unroll
        for (int kh = 0; kh < 2; ++kh) {
            int p = 64 * w + 16 * mt + lc;
            int orow = (p & 3) * H2 + (p >> 2);
            float tmp[8];
            const float* src = Whh + (size_t)orow * H2 + 32 * kh + 8 * lg;
#pragma unroll
            for (int e = 0; e < 8; ++e) tmp[e] = src[e];
            wf[mt][kh] = pack8(tmp);
        }
    }
    // per-acc-row params: rows p = 64w+16mt+4lg+r
    float bia[4][4], wx0[4][4], wx1[4][4];
#pragma unroll
    for (int mt = 0; mt < 4; ++mt)
#pragma unroll
        for (int r = 0; r < 4; ++r) {
            int p = 64 * w + 16 * mt + 4 * lg + r;
            int orow = (p & 3) * H2 + (p >> 2);
            bia[mt][r] = a.bih[dir][orow] + a.bhh[dir][orow];
            wx0[mt][r] = Wih[orow * 2 + 0];
            wx1[mt][r] = Wih[orow * 2 + 1];
        }

    __shared__ unsigned short Hb[2][8][16][8];   // [buf][k>>3][batch][k&7]
    ((unsigned long long*)Hb)[tid] = 0ULL;       // zero buf 0 (2048B)

    const bool isTraj = (prob >= 4);
    float* outp = a.outs + (size_t)(isTraj ? (prob - 4) : 0) * BB * TT * HH;
    const float2* xg2 = (const float2*)a.x[prob];
    const int c = b0 + lc;

    float cst[4] = {0.f, 0.f, 0.f, 0.f};
    float2 xr = xg2[(size_t)c * TT + (dir ? TT - 1 : 0)];
    int cur = 0;
    __syncthreads();

    for (int t = 0; t < TT; ++t) {
        f32x4 acc[4];
#pragma unroll
        for (int mt = 0; mt < 4; ++mt) {
            f32x4 v;
#pragma unroll
            for (int r = 0; r < 4; ++r)
                v[r] = bia[mt][r] + wx0[mt][r] * xr.x + wx1[mt][r] * xr.y;
            acc[mt] = v;
        }
        // prefetch next x
        {
            int tn = (t + 1 < TT) ? t + 1 : t;
            xr = xg2[(size_t)c * TT + (dir ? TT - 1 - tn : tn)];
        }
#pragma unroll
        for (int kh = 0; kh < 2; ++kh) {
            bf16x8 bfrag = *(const bf16x8*)&Hb[cur][4 * kh + lg][lc][0];
#pragma unroll
            for (int mt = 0; mt < 4; ++mt)
                acc[mt] = MFMA16(wf[mt][kh], bfrag, acc[mt]);
        }
        const int nxt = cur ^ 1;
        const int tcol = dir ? (TT - 1 - t) : t;
#pragma unroll
        for (int mt = 0; mt < 4; ++mt) {
            float gi = acc[mt][0], gf = acc[mt][1], gg = acc[mt][2], go = acc[mt][3];
            cst[mt] = fsigm(gf) * cst[mt] + fsigm(gi) * ftanh(gg);
            float h = fsigm(go) * ftanh(cst[mt]);
            int hc = 16 * w + 4 * mt + lg;
            Hb[nxt][hc >> 3][lc][hc & 7] = f2bf(h);
            if (isTraj)
                outp[((size_t)c * TT + tcol) * HH + dir * H2 + hc] = h;
            if (t == TT - 1)
                a.hid[((size_t)prob * BB + c) * HH + dir * H2 + hc] = h;
        }
        __syncthreads();
        cur = nxt;
    }
}

// ------------------- mve Wih_x transpose (permuted cols) --------------------
__global__ void k_wxT(const float* __restrict__ Wm, float* __restrict__ WxT) {
    int idx = blockIdx.x * 256 + threadIdx.x;   // 65536
    int k = idx >> 9, j = idx & 511;
    int p = 4 * (j & 127) + (j >> 7);
    WxT[(size_t)k * GM + p] = Wm[(size_t)j * (2 * HH) + k];
}

// ---------------- xproj GEMM: [B*T,128] x [128,512] -> bf16 -----------------
__global__ __launch_bounds__(256) void k_xproj(const float* __restrict__ A,
                                               const float* __restrict__ WxT,
                                               unsigned short* __restrict__ C) {
    __shared__ float As[64][128];
    __shared__ float Ws[128][64];
    const int m0 = blockIdx.x * 64;
    const int n0 = blockIdx.y * 64;
    const int tid = threadIdx.x;
#pragma unroll
    for (int it = 0; it < 8; ++it) {
        int lin = it * 256 + tid;
        int m = lin >> 5, k4 = lin & 31;
        float4 v = ((const float4*)(A + (size_t)(m0 + m) * HH))[k4];
        *(float4*)&As[m][4 * k4] = v;
    }
#pragma unroll
    for (int it = 0; it < 8; ++it) {
        int lin = it * 256 + tid;
        int k = lin >> 4, n4 = lin & 15;
        float4 v = ((const float4*)(WxT + (size_t)k * GM + n0))[n4];
        *(float4*)&Ws[k][4 * n4] = v;
    }
    __syncthreads();
    const int tm = (tid >> 4) << 2;
    const int tn = (tid & 15) << 2;
    float acc[4][4];
#pragma unroll
    for (int i = 0; i < 4; ++i)
        acc[i][0] = acc[i][1] = acc[i][2] = acc[i][3] = 0.f;
#pragma unroll
    for (int k4 = 0; k4 < 32; ++k4) {
        float4 av0 = *(const float4*)&As[tm + 0][4 * k4];
        float4 av1 = *(const float4*)&As[tm + 1][4 * k4];
        float4 av2 = *(const float4*)&As[tm + 2][4 * k4];
        float4 av3 = *(const float4*)&As[tm + 3][4 * k4];
        float4 wv0 = *(const float4*)&Ws[4 * k4 + 0][tn];
        float4 wv1 = *(const float4*)&Ws[4 * k4 + 1][tn];
        float4 wv2 = *(const float4*)&Ws[4 * k4 + 2][tn];
        float4 wv3 = *(const float4*)&Ws[4 * k4 + 3][tn];
#define ROWX(i, AV)                                                        \
        acc[i][0] += AV.x*wv0.x + AV.y*wv1.x + AV.z*wv2.x + AV.w*wv3.x;     \
        acc[i][1] += AV.x*wv0.y + AV.y*wv1.y + AV.z*wv2.y + AV.w*wv3.y;     \
        acc[i][2] += AV.x*wv0.z + AV.y*wv1.z + AV.z*wv2.z + AV.w*wv3.z;     \
        acc[i][3] += AV.x*wv0.w + AV.y*wv1.w + AV.z*wv2.w + AV.w*wv3.w;
        ROWX(0, av0) ROWX(1, av1) ROWX(2, av2) ROWX(3, av3)
#undef ROWX
    }
#pragma unroll
    for (int i = 0; i < 4; ++i) {
        size_t row = (size_t)(m0 + tm + i);
        unsigned short* cp = C + row * GM + n0 + tn;
        ushort4 u;
        u.x = f2bf(acc[i][0]); u.y = f2bf(acc[i][1]);
        u.z = f2bf(acc[i][2]); u.w = f2bf(acc[i][3]);
        *(ushort4*)cp = u;
    }
}

// ------------- hp: hidden_l @ WihR.T + bias (permuted rows) -----------------
__global__ __launch_bounds__(256) void k_hp(const float* __restrict__ hidl,
                                            const float* __restrict__ Wih,
                                            const float* __restrict__ bih,
                                            const float* __restrict__ bhh,
                                            float* __restrict__ hp) {
    int traj = blockIdx.x, b = blockIdx.y;
    int j = threadIdx.x;
    __shared__ float hs[HH];
    if (j < HH) hs[j] = hidl[((size_t)traj * BB + b) * HH + j];
    __syncthreads();
    const float4* hs4 = (const float4*)hs;
#pragma unroll
    for (int rr = 0; rr < 2; ++rr) {
        int row = j + 256 * rr;
        float acc = bih[row] + bhh[row];
        const float4* w4 = (const float4*)(Wih + (size_t)row * (2 * HH) + HH);
#pragma unroll
        for (int k4 = 0; k4 < HH / 4; ++k4) {
            float4 wv = w4[k4], hv = hs4[k4];
            acc += wv.x * hv.x + wv.y * hv.y + wv.z * hv.z + wv.w * hv.w;
        }
        int p = 4 * (row & 127) + (row >> 7);
        hp[((size_t)traj * BB + b) * GM + p] = acc;
    }
}

// ============================= mve scan (MFMA) ==============================
struct MveArgs {
    const unsigned short* xp;   // [3][B][T][512] bf16, cols permuted 4h+q
    const float* hp;            // [3][B][512] fp32, rows permuted
    const float* Whh;           // [512][128]
    float* mout;                // d_out+512: [3][B][T][HH] cell states
};

__global__ __launch_bounds__(512) void k_mve_mfma(MveArgs a) {
    const int blk  = blockIdx.x;   // 24
    const int traj = blk >> 3;
    const int b0   = (blk & 7) * 16;
    const int tid  = threadIdx.x;
    const int w    = tid >> 6;     // 0..7
    const int l    = tid & 63;
    const int lg   = l >> 4;
    const int lc   = l & 15;
    const int c    = b0 + lc;

    // weights: rows p = 64w+16mt+lc, k = 32kh+8lg+e; orig = (p&3)*128 + (p>>2)
    bf16x8 wf[4][4];
#pragma unroll
    for (int mt = 0; mt < 4; ++mt) {
#pragma unroll
        for (int kh = 0; kh < 4; ++kh) {
            int p = 64 * w + 16 * mt + lc;
            int orow = (p & 3) * HH + (p >> 2);
            float tmp[8];
            const float* src = a.Whh + (size_t)orow * HH + 32 * kh + 8 * lg;
#pragma unroll
            for (int e = 0; e < 8; ++e) tmp[e] = src[e];
            wf[mt][kh] = pack8(tmp);
        }
    }
    // hp values: rows p = 64w+16mt+4lg+r (already permuted in hp buffer)
    float hpv[4][4];
#pragma unroll
    for (int mt = 0; mt < 4; ++mt)
#pragma unroll
        for (int r = 0; r < 4; ++r)
            hpv[mt][r] = a.hp[((size_t)traj * BB + c) * GM + 64 * w + 16 * mt + 4 * lg + r];

    __shared__ unsigned short Hb[2][16][16][8];   // [buf][k>>3][batch][k&7]
    ((unsigned long long*)Hb)[tid] = 0ULL;        // zero buf 0 (4096B)

    const unsigned short* xpp = a.xp + (size_t)traj * BB * TT * GM;
    float* mo = a.mout + (size_t)traj * BB * TT * HH;

    float cst[4] = {0.f, 0.f, 0.f, 0.f};
    ushort4 xq[4];
#pragma unroll
    for (int mt = 0; mt < 4; ++mt) {
        int hc = 16 * w + 4 * mt + lg;
        xq[mt] = *(const ushort4*)&xpp[((size_t)c * TT + 0) * GM + 4 * hc];
    }
    int cur = 0;
    __syncthreads();

    for (int t = 0; t < TT; ++t) {
        f32x4 acc[4];
#pragma unroll
        for (int mt = 0; mt < 4; ++mt) {
            f32x4 v;
            v[0] = hpv[mt][0] + bfu(xq[mt].x);
            v[1] = hpv[mt][1] + bfu(xq[mt].y);
            v[2] = hpv[mt][2] + bfu(xq[mt].z);
            v[3] = hpv[mt][3] + bfu(xq[mt].w);
            acc[mt] = v;
        }
        // prefetch next xp
        {
            int tn = (t + 1 < TT) ? t + 1 : t;
#pragma unroll
            for (int mt = 0; mt < 4; ++mt) {
                int hc = 16 * w + 4 * mt + lg;
                xq[mt] = *(const ushort4*)&xpp[((size_t)c * TT + tn) * GM + 4 * hc];
            }
        }
#pragma unroll
        for (int kh = 0; kh < 4; ++kh) {
            bf16x8 bfrag = *(const bf16x8*)&Hb[cur][4 * kh + lg][lc][0];
#pragma unroll
            for (int mt = 0; mt < 4; ++mt)
                acc[mt] = MFMA16(wf[mt][kh], bfrag, acc[mt]);
        }
        const int nxt = cur ^ 1;
#pragma unroll
        for (int mt = 0; mt < 4; ++mt) {
            float gi = acc[mt][0], gf = acc[mt][1], gg = acc[mt][2], go = acc[mt][3];
            cst[mt] = fsigm(gf) * cst[mt] + fsigm(gi) * ftanh(gg);
            float h = fsigm(go) * ftanh(cst[mt]);
            int hc = 16 * w + 4 * mt + lg;
            Hb[nxt][hc >> 3][lc][hc & 7] = f2bf(h);
            mo[((size_t)c * TT + t) * HH + hc] = cst[mt];   // CELL state
        }
        __syncthreads();
        cur = nxt;
    }
}

// ----------------------------------------------------------------- sim ------
__global__ __launch_bounds__(128) void k_sim(const float* __restrict__ hid,
                                             const float* __restrict__ Wi, const float* __restrict__ bi,
                                             const float* __restrict__ Wc, const float* __restrict__ bc,
                                             const float* __restrict__ Wo, const float* __restrict__ bo,
                                             float* __restrict__ simv) {
    int which = blockIdx.x >> 7;
    int b = blockIdx.x & 127;
    int j = threadIdx.x;
    __shared__ float hs[HH];
    hs[j] = hid[((size_t)which * BB + b) * HH + j];
    __syncthreads();
    float ai = bi[j], ac = bc[j], ao = bo[j];
    const float4* wi4 = (const float4*)(Wi + (size_t)j * HH);
    const float4* wc4 = (const float4*)(Wc + (size_t)j * HH);
    const float4* wo4 = (const float4*)(Wo + (size_t)j * HH);
#pragma unroll
    for (int k4 = 0; k4 < HH / 4; ++k4) {
        float4 h = ((const float4*)hs)[k4];
        float4 vi = wi4[k4]; ai += vi.x*h.x + vi.y*h.y + vi.z*h.z + vi.w*h.w;
        float4 vc = wc4[k4]; ac += vc.x*h.x + vc.y*h.y + vc.z*h.z + vc.w*h.w;
        float4 vo = wo4[k4]; ao += vo.x*h.x + vo.y*h.y + vo.z*h.z + vo.w*h.w;
    }
    float Cv = fsigm(ai) * ftanh(ac);
    float v = fsigm(ao) * ftanh(Cv) + hs[j];
    simv[((size_t)which * BB + b) * HH + j] = v;
}

// ------------------------------------------------------------------ l2 ------
__global__ __launch_bounds__(64) void k_l2(const float* __restrict__ simv,
                                           float* __restrict__ out) {
    int p = blockIdx.x >> 7;
    int b = blockIdx.x & 127;
    int aw, cw;
    switch (p) {
        case 0: aw = 0; cw = 2; break;
        case 1: aw = 1; cw = 3; break;
        case 2: aw = 4; cw = 5; break;
        default: aw = 4; cw = 6; break;
    }
    int l = threadIdx.x;
    const float* va = simv + ((size_t)aw * BB + b) * HH;
    const float* vc = simv + ((size_t)cw * BB + b) * HH;
    float d0 = va[l] - vc[l];
    float d1 = va[l + 64] - vc[l + 64];
    float s = d0 * d0 + d1 * d1;
#pragma unroll
    for (int m = 32; m >= 1; m >>= 1) s += __shfl_xor(s, m, 64);
    if (l == 0) out[p * BB + b] = expf(-sqrtf(s));
}

// -------------------------------------------------------------- launcher ----
extern "C" void kernel_launch(void* const* d_in, const int* in_sizes, int n_in,
                              void* d_out_v, int out_size, void* d_ws, size_t ws_size,
                              hipStream_t stream) {
    const float* mWih  = (const float*)d_in[15];
    const float* mWhh  = (const float*)d_in[16];
    const float* mbih  = (const float*)d_in[17];
    const float* mbhh  = (const float*)d_in[18];
    const float* sWi   = (const float*)d_in[19];
    const float* sbi   = (const float*)d_in[20];
    const float* sWc   = (const float*)d_in[21];
    const float* sbc   = (const float*)d_in[22];
    const float* sWo   = (const float*)d_in[23];
    const float* sbo   = (const float*)d_in[24];

    constexpr size_t OUTS_LEN = (size_t)3 * BB * TT * HH;   // 25165824 f32
    constexpr size_t HID_LEN  = (size_t)7 * BB * HH;        // 114688
    constexpr size_t WXT_LEN  = (size_t)HH * GM;            // 65536
    constexpr size_t SIMV_LEN = HID_LEN;
    constexpr size_t HP_LEN   = (size_t)3 * BB * GM;        // 196608
    constexpr size_t XP_LEN   = (size_t)BB * TT * GM;       // 33554432 bf16/traj

    float* ws    = (float*)d_ws;
    float* outs  = ws;
    float* hid   = outs + OUTS_LEN;
    float* wxT   = hid + HID_LEN;
    float* simv  = wxT + WXT_LEN;
    float* hp    = simv + SIMV_LEN;
    unsigned short* xpb = (unsigned short*)(hp + HP_LEN);

    float* dout = (float*)d_out_v;
    float* mout = dout + 512;

    BiArgs ba;
    for (int i = 0; i < 7; ++i) ba.x[i] = (const float*)d_in[i];
    ba.Wih[0] = (const float*)d_in[7];  ba.Whh[0] = (const float*)d_in[8];
    ba.bih[0] = (const float*)d_in[9];  ba.bhh[0] = (const float*)d_in[10];
    ba.Wih[1] = (const float*)d_in[11]; ba.Whh[1] = (const float*)d_in[12];
    ba.bih[1] = (const float*)d_in[13]; ba.bhh[1] = (const float*)d_in[14];
    ba.outs = outs; ba.hid = hid;

    k_wxT<<<256, 256, 0, stream>>>(mWih, wxT);
    k_bilstm_mfma<<<112, 256, 0, stream>>>(ba);
    k_hp<<<dim3(3, BB), 256, 0, stream>>>(hid + (size_t)4 * BB * HH, mWih, mbih, mbhh, hp);

    dim3 gx(BB * TT / 64, GM / 64);
    for (int tr = 0; tr < 3; ++tr)
        k_xproj<<<gx, 256, 0, stream>>>(outs + (size_t)tr * BB * TT * HH, wxT,
                                        xpb + (size_t)tr * XP_LEN);

    MveArgs ma;
    ma.xp = xpb; ma.hp = hp; ma.Whh = mWhh; ma.mout = mout;
    k_mve_mfma<<<24, 512, 0, stream>>>(ma);

    k_sim<<<7 * BB, 128, 0, stream>>>(hid, sWi, sbi, sWc, sbc, sWo, sbo, simv);
    k_l2<<<4 * BB, 64, 0, stream>>>(simv, dout);
}